// Round 5
// baseline (2181.276 us; speedup 1.0000x reference)
//
#include <hip/hip_runtime.h>
#include <math.h>

#define DMODEL 768
#define NHEAD 12
#define DHEAD 64
#define HIDDEN 3072
#define NLAYER 6
#define SEQ 1024

typedef unsigned short u16;
typedef __attribute__((ext_vector_type(8))) short short8;
typedef __attribute__((ext_vector_type(4))) float f32x4;

__device__ __forceinline__ u16 f2bf(float f) {
    union { float f; unsigned u; } v; v.f = f;
    unsigned u = v.u;
    return (u16)((u + 0x7fffu + ((u >> 16) & 1u)) >> 16);
}
__device__ __forceinline__ float bf2f(u16 b) {
    union { unsigned u; float f; } v; v.u = ((unsigned)b) << 16; return v.f;
}

// async global->LDS, 16B/lane; LDS base wave-uniform (HW adds lane*16)
__device__ __forceinline__ void async16(const void* g, void* l) {
    __builtin_amdgcn_global_load_lds(
        (const __attribute__((address_space(1))) unsigned int*)g,
        (__attribute__((address_space(3))) unsigned int*)l, 16, 0, 0);
}

// ---------------------------------------------------------------- reductions
__device__ __forceinline__ float block_sum(float v, float* red) {
    int tid = threadIdx.x;
    red[tid] = v;
    __syncthreads();
#pragma unroll
    for (int s = 128; s > 0; s >>= 1) {
        if (tid < s) red[tid] += red[tid + s];
        __syncthreads();
    }
    float r = red[0];
    __syncthreads();
    return r;
}
__device__ __forceinline__ float block_max(float v, float* red) {
    int tid = threadIdx.x;
    red[tid] = v;
    __syncthreads();
#pragma unroll
    for (int s = 128; s > 0; s >>= 1) {
        if (tid < s) red[tid] = fmaxf(red[tid], red[tid + s]);
        __syncthreads();
    }
    float r = red[0];
    __syncthreads();
    return r;
}

// ---------------------------------------------------------------- small kernels
__global__ __launch_bounds__(256) void add_pe(const float* __restrict__ a,
                                              const float* __restrict__ b,
                                              float* __restrict__ o,
                                              u16* __restrict__ ob, int n) {
    int i = blockIdx.x * 256 + threadIdx.x;
    if (i < n) { float v = a[i] + b[i]; o[i] = v; ob[i] = f2bf(v); }
}

__global__ __launch_bounds__(256) void cvt_bf16(const float* __restrict__ src,
                                                u16* __restrict__ dst,
                                                long long per, long long sls, long long dls) {
    long long i = ((long long)blockIdx.x * 256 + threadIdx.x) * 4;
    if (i >= per) return;
    const float* s = src + (long long)blockIdx.y * sls + i;
    u16* d = dst + (long long)blockIdx.y * dls + i;
    float4 v = *(const float4*)s;
    ushort4 o;
    o.x = f2bf(v.x); o.y = f2bf(v.y); o.z = f2bf(v.z); o.w = f2bf(v.w);
    *(ushort4*)d = o;
}

// ---------------------------------------------------------------- MFMA GEMM (2-phase dbuf)
// C[N x M] = A[N x K](bf16) * B[M x K]^T (+bias) (+relu)
// Optional: columns >= vt_col0 stored TRANSPOSED to vt_out[(col-vt_col0)][row].
template<int TM, int TN>
__global__ __launch_bounds__(256) void gemm_mfma(
    const u16* __restrict__ A, int lda,
    const void* __restrict__ Bp, int ldb, int b_f32,
    const float* __restrict__ bias,
    void* __restrict__ Cp, int ldc, int c_bf16,
    u16* __restrict__ vt_out, int vt_col0,
    int K, int relu)
{
    constexpr int FM = TM / 32, FN = TN / 32;
    __shared__ __align__(16) u16 As[2][TM * 64];
    __shared__ __align__(16) u16 Bs[2][TN * 64];

    const u16*   B16 = (const u16*)Bp;
    const float* B32 = (const float*)Bp;
    u16*   C16 = (u16*)Cp;
    float* C32 = (float*)Cp;

    const int t = threadIdx.x, lane = t & 63, w = t >> 6;
    const int wy = w >> 1, wx = w & 1;
    const int n0 = blockIdx.y * TM, m0 = blockIdx.x * TN;

    auto stage = [&](int b, int k0) {
#pragma unroll
        for (int i = 0; i < TM / 32; ++i) {
            int L = i * 256 + t;
            int row = L >> 3, cp = L & 7, c = cp ^ (row & 7);
            async16(A + (long long)(n0 + row) * lda + k0 + (c << 3),
                    &As[b][(i * 256 + w * 64) * 8]);
        }
        if (!b_f32) {
#pragma unroll
            for (int i = 0; i < TN / 32; ++i) {
                int L = i * 256 + t;
                int row = L >> 3, cp = L & 7, c = cp ^ (row & 7);
                async16(B16 + (long long)(m0 + row) * ldb + k0 + (c << 3),
                        &Bs[b][(i * 256 + w * 64) * 8]);
            }
        } else {
#pragma unroll
            for (int i = 0; i < TN / 32; ++i) {
                int L = i * 256 + t;
                int row = L >> 3, cp = L & 7, c = cp ^ (row & 7);
                const float* s = B32 + (long long)(m0 + row) * ldb + k0 + (c << 3);
                float4 x = *(const float4*)s;
                float4 y = *(const float4*)(s + 4);
                uint4 pk;
                pk.x = (unsigned)f2bf(x.x) | ((unsigned)f2bf(x.y) << 16);
                pk.y = (unsigned)f2bf(x.z) | ((unsigned)f2bf(x.w) << 16);
                pk.z = (unsigned)f2bf(y.x) | ((unsigned)f2bf(y.y) << 16);
                pk.w = (unsigned)f2bf(y.z) | ((unsigned)f2bf(y.w) << 16);
                *(uint4*)&Bs[b][row * 64 + cp * 8] = pk;
            }
        }
    };

    const int nk = K / 64;
    stage(0, 0);
    __syncthreads();

    f32x4 acc[FM][FN] = {};

    for (int tt = 0; tt < nk; ++tt) {
        const int cur = tt & 1;
        if (tt + 1 < nk) stage(cur ^ 1, (tt + 1) * 64);   // overlap: issue next tile

        const u16* Ac = As[cur];
        const u16* Bc = Bs[cur];
#pragma unroll
        for (int kk = 0; kk < 2; ++kk) {
            short8 af[FM], bfv[FN];
            const int cb = kk * 4 + (lane >> 4);
#pragma unroll
            for (int m = 0; m < FM; ++m) {
                int R = wy * (TM / 2) + m * 16 + (lane & 15);
                af[m] = *(const short8*)&Ac[R * 64 + ((cb ^ (R & 7)) << 3)];
            }
#pragma unroll
            for (int n = 0; n < FN; ++n) {
                int R = wx * (TN / 2) + n * 16 + (lane & 15);
                bfv[n] = *(const short8*)&Bc[R * 64 + ((cb ^ (R & 7)) << 3)];
            }
#pragma unroll
            for (int m = 0; m < FM; ++m)
#pragma unroll
                for (int n = 0; n < FN; ++n)
                    acc[m][n] = __builtin_amdgcn_mfma_f32_16x16x32_bf16(af[m], bfv[n], acc[m][n], 0, 0, 0);
        }
        __syncthreads();   // drains next-tile async loads (issued before compute) + wave sync
    }

    const int cj = lane & 15, ci0 = (lane >> 4) << 2;
#pragma unroll
    for (int m = 0; m < FM; ++m) {
#pragma unroll
        for (int n = 0; n < FN; ++n) {
            int col = m0 + wx * (TN / 2) + n * 16 + cj;
            bool to_vt = vt_out && (col >= vt_col0);
            float bv = bias ? bias[col] : 0.0f;
#pragma unroll
            for (int r = 0; r < 4; ++r) {
                int row = n0 + wy * (TM / 2) + m * 16 + ci0 + r;
                float v = acc[m][n][r] + bv;
                if (relu) v = fmaxf(v, 0.0f);
                if (to_vt)        vt_out[(long long)(col - vt_col0) * SEQ + row] = f2bf(v);
                else if (c_bf16)  C16[(long long)row * ldc + col] = f2bf(v);
                else              C32[(long long)row * ldc + col] = v;
            }
        }
    }
}

// ---------------------------------------------------------------- fused flash attention (2-phase dbuf, 1 barrier/tile)
template<int CAUSAL>
__global__ __launch_bounds__(256) void attn_fused(
    const u16* __restrict__ Qg,   // qkv base (Q columns)
    const u16* __restrict__ Kg,   // qkv base + DMODEL (K columns)
    const u16* __restrict__ VT,   // [DMODEL][SEQ]
    u16* __restrict__ O)          // [SEQ][DMODEL]
{
    const int h  = blockIdx.y;
    const int qt = blockIdx.x;
    const int q0 = qt * 64;
    const int t = threadIdx.x, lane = t & 63, w = t >> 6;

    __shared__ __align__(16) u16 Ks[2][64 * 64];
    __shared__ __align__(16) u16 Vs[2][64 * 64];
    __shared__ __align__(16) u16 Ps[4][16 * 64];

    // Q fragments: wave w owns q-rows q0 + w*16 .. +15 (in regs)
    short8 qf[2];
    {
        int qrow = q0 + w * 16 + (lane & 15);
        const u16* qp = Qg + (long long)qrow * (3 * DMODEL) + h * DHEAD + ((lane >> 4) << 3);
        qf[0] = *(const short8*)qp;
        qf[1] = *(const short8*)(qp + 32);
    }

    auto stage = [&](int b, int kt) {
#pragma unroll
        for (int i = 0; i < 2; ++i) {
            int LL = i * 256 + t;
            int row = LL >> 3, cp = LL & 7, c = cp ^ (row & 7);
            async16(Kg + (long long)(kt * 64 + row) * (3 * DMODEL) + h * DHEAD + (c << 3),
                    &Ks[b][(i * 256 + w * 64) * 8]);
            async16(VT + (long long)(h * DHEAD + row) * SEQ + kt * 64 + (c << 3),
                    &Vs[b][(i * 256 + w * 64) * 8]);
        }
    };

    f32x4 o_acc[4] = {};
    float m_r[4], l_r[4];
#pragma unroll
    for (int r = 0; r < 4; ++r) { m_r[r] = -3.0e38f; l_r[r] = 0.f; }

    const int nt = CAUSAL ? (qt + 1) : (SEQ / 64);

    stage(0, 0);
    __syncthreads();

    for (int kt = 0; kt < nt; ++kt) {
        const int cur = kt & 1;
        if (kt + 1 < nt) stage(cur ^ 1, kt + 1);   // overlap next K/V tile

        // S = Q K^T
        f32x4 s[4] = {};
#pragma unroll
        for (int kk = 0; kk < 2; ++kk) {
            const int cb = kk * 4 + (lane >> 4);
#pragma unroll
            for (int n = 0; n < 4; ++n) {
                int R = n * 16 + (lane & 15);
                short8 kf = *(const short8*)&Ks[cur][R * 64 + ((cb ^ (R & 7)) << 3)];
                s[n] = __builtin_amdgcn_mfma_f32_16x16x32_bf16(qf[kk], kf, s[n], 0, 0, 0);
            }
        }

        // scale + diagonal causal mask
#pragma unroll
        for (int n = 0; n < 4; ++n) {
            int keyl = n * 16 + (lane & 15);
#pragma unroll
            for (int r = 0; r < 4; ++r) {
                float v = s[n][r] * 0.125f;
                if (CAUSAL && kt == qt) {
                    int ql = w * 16 + ((lane >> 4) << 2) + r;
                    if (keyl > ql) v -= 10000.0f;
                }
                s[n][r] = v;
            }
        }

        // online softmax per q-row
#pragma unroll
        for (int r = 0; r < 4; ++r) {
            float vm = fmaxf(fmaxf(s[0][r], s[1][r]), fmaxf(s[2][r], s[3][r]));
            vm = fmaxf(vm, __shfl_xor(vm, 1));
            vm = fmaxf(vm, __shfl_xor(vm, 2));
            vm = fmaxf(vm, __shfl_xor(vm, 4));
            vm = fmaxf(vm, __shfl_xor(vm, 8));
            float mn = fmaxf(m_r[r], vm);
            float sf = __expf(m_r[r] - mn);
            m_r[r] = mn;
            float rowsum = 0.f;
#pragma unroll
            for (int n = 0; n < 4; ++n) {
                float p = __expf(s[n][r] - mn);
                s[n][r] = p;
                rowsum += p;
            }
            rowsum += __shfl_xor(rowsum, 1);
            rowsum += __shfl_xor(rowsum, 2);
            rowsum += __shfl_xor(rowsum, 4);
            rowsum += __shfl_xor(rowsum, 8);
            l_r[r] = l_r[r] * sf + rowsum;
#pragma unroll
            for (int d = 0; d < 4; ++d) o_acc[d][r] *= sf;
        }

        // P (C-layout) -> Ps[w] (wave-private; only in-wave lgkm ordering needed)
#pragma unroll
        for (int n = 0; n < 4; ++n) {
            int jh = lane & 7;
            int chunk = n * 2 + ((lane & 15) >> 3);
#pragma unroll
            for (int r = 0; r < 4; ++r) {
                int q = ((lane >> 4) << 2) + r;
                Ps[w][q * 64 + ((chunk ^ (q & 7)) << 3) + jh] = f2bf(s[n][r]);
            }
        }

        // O += P V
#pragma unroll
        for (int kk = 0; kk < 2; ++kk) {
            int q = lane & 15;
            int chunk = (lane >> 4) + kk * 4;
            short8 pf = *(const short8*)&Ps[w][q * 64 + ((chunk ^ (q & 7)) << 3)];
            const int cb = kk * 4 + (lane >> 4);
#pragma unroll
            for (int d = 0; d < 4; ++d) {
                int R = d * 16 + (lane & 15);
                short8 vf = *(const short8*)&Vs[cur][R * 64 + ((cb ^ (R & 7)) << 3)];
                o_acc[d] = __builtin_amdgcn_mfma_f32_16x16x32_bf16(pf, vf, o_acc[d], 0, 0, 0);
            }
        }
        __syncthreads();   // next-tile staging drained; all waves done with cur
    }

    // normalize + write
#pragma unroll
    for (int r = 0; r < 4; ++r) {
        float inv = 1.0f / l_r[r];
        int row = q0 + w * 16 + ((lane >> 4) << 2) + r;
#pragma unroll
        for (int d = 0; d < 4; ++d) {
            int col = h * DHEAD + d * 16 + (lane & 15);
            O[(long long)row * DMODEL + col] = f2bf(o_acc[d][r] * inv);
        }
    }
}

// ---------------------------------------------------------------- f32 row softmax (final)
__global__ __launch_bounds__(256) void softmax_f32(const float* __restrict__ in,
                                                   float* __restrict__ out, int width) {
    const float* row = in + (long long)blockIdx.x * width;
    float* orow = out + (long long)blockIdx.x * width;
    int tid = threadIdx.x;
    __shared__ float red[256];
    int nf4 = width >> 2;
    float4 v = {-1e30f, -1e30f, -1e30f, -1e30f};
    if (tid < nf4) v = ((const float4*)row)[tid];
    float mx = fmaxf(fmaxf(v.x, v.y), fmaxf(v.z, v.w));
    mx = block_max(mx, red);
    float4 e = {0.f, 0.f, 0.f, 0.f};
    float s = 0.f;
    if (tid < nf4) {
        e.x = __expf(v.x - mx); e.y = __expf(v.y - mx);
        e.z = __expf(v.z - mx); e.w = __expf(v.w - mx);
        s = e.x + e.y + e.z + e.w;
    }
    s = block_sum(s, red);
    float inv = 1.0f / s;
    if (tid < nf4) {
        e.x *= inv; e.y *= inv; e.z *= inv; e.w *= inv;
        ((float4*)orow)[tid] = e;
    }
}

// ---------------------------------------------------------------- x = LN(x + fx); emits f32 + bf16
__global__ __launch_bounds__(256) void ln_res_kernel(float* __restrict__ x,
                                                     const float* __restrict__ fx,
                                                     const float* __restrict__ ga,
                                                     const float* __restrict__ gb,
                                                     u16* __restrict__ xb) {
    long long row = blockIdx.x;
    float* xr = x + row * DMODEL;
    const float* fr = fx + row * DMODEL;
    u16* xbr = xb + row * DMODEL;
    int tid = threadIdx.x;
    __shared__ float red[256];

    float4 tv = {0.f, 0.f, 0.f, 0.f};
    if (tid < 192) {
        float4 a = ((const float4*)xr)[tid];
        float4 f = ((const float4*)fr)[tid];
        tv.x = a.x + f.x; tv.y = a.y + f.y; tv.z = a.z + f.z; tv.w = a.w + f.w;
    }
    float sum = tv.x + tv.y + tv.z + tv.w;
    sum = block_sum(sum, red);
    float mean = sum * (1.0f / (float)DMODEL);

    float4 d = {0.f, 0.f, 0.f, 0.f};
    float ss = 0.f;
    if (tid < 192) {
        d.x = tv.x - mean; d.y = tv.y - mean; d.z = tv.z - mean; d.w = tv.w - mean;
        ss = d.x * d.x + d.y * d.y + d.z * d.z + d.w * d.w;
    }
    ss = block_sum(ss, red);
    float stdv = sqrtf(ss / (float)(DMODEL - 1));
    float inv = 1.0f / (stdv + 1e-6f);

    if (tid < 192) {
        float4 A = ((const float4*)ga)[tid];
        float4 B = ((const float4*)gb)[tid];
        float4 o;
        o.x = A.x * d.x * inv + B.x;
        o.y = A.y * d.y * inv + B.y;
        o.z = A.z * d.z * inv + B.z;
        o.w = A.w * d.w * inv + B.w;
        ((float4*)xr)[tid] = o;
        ushort4 ob;
        ob.x = f2bf(o.x); ob.y = f2bf(o.y); ob.z = f2bf(o.z); ob.w = f2bf(o.w);
        ((ushort4*)xbr)[tid] = ob;
    }
}

// ---------------------------------------------------------------- host
struct GArg {
    const u16* A; int lda;
    const void* B; int ldb; int b_f32;
    const float* bias;
    void* C; int ldc; int c_bf16;
    u16* vt; int vt_col0;
    int N, M, K; int relu;
};
static inline void g64(hipStream_t st, const GArg& a) {
    dim3 grid(a.M / 64, a.N / 64);
    hipLaunchKernelGGL((gemm_mfma<64, 64>), grid, dim3(256), 0, st,
                       a.A, a.lda, a.B, a.ldb, a.b_f32, a.bias, a.C, a.ldc, a.c_bf16,
                       a.vt, a.vt_col0, a.K, a.relu);
}
static inline void g128(hipStream_t st, const GArg& a) {
    dim3 grid(a.M / 128, a.N / 128);
    hipLaunchKernelGGL((gemm_mfma<128, 128>), grid, dim3(256), 0, st,
                       a.A, a.lda, a.B, a.ldb, a.b_f32, a.bias, a.C, a.ldc, a.c_bf16,
                       a.vt, a.vt_col0, a.K, a.relu);
}

extern "C" void kernel_launch(void* const* d_in, const int* in_sizes, int n_in,
                              void* d_out, int out_size, void* d_ws, size_t ws_size,
                              hipStream_t stream) {
    const float* xl      = (const float*)d_in[0];
    const float* dl      = (const float*)d_in[1];
    const float* pe      = (const float*)d_in[2];
    const float* enc_wq  = (const float*)d_in[3];
    const float* enc_wk  = (const float*)d_in[4];
    const float* enc_wv  = (const float*)d_in[5];
    const float* enc_wo  = (const float*)d_in[6];
    const float* enc_bo  = (const float*)d_in[7];
    const float* enc_lna = (const float*)d_in[8];
    const float* enc_lnb = (const float*)d_in[9];
    const float* enc_w1  = (const float*)d_in[10];
    const float* enc_b1  = (const float*)d_in[11];
    const float* enc_w2  = (const float*)d_in[12];
    const float* enc_b2  = (const float*)d_in[13];
    const float* dec_wq  = (const float*)d_in[14];
    const float* dec_wk  = (const float*)d_in[15];
    const float* dec_wv  = (const float*)d_in[16];
    const float* dec_wo  = (const float*)d_in[17];
    const float* dec_bo  = (const float*)d_in[18];
    const float* dec_cwq = (const float*)d_in[19];
    const float* dec_cwk = (const float*)d_in[20];
    const float* dec_cwv = (const float*)d_in[21];
    const float* dec_cwo = (const float*)d_in[22];
    const float* dec_cbo = (const float*)d_in[23];
    const float* dec_lna = (const float*)d_in[24];
    const float* dec_lnb = (const float*)d_in[25];
    const float* dec_w1  = (const float*)d_in[26];
    const float* dec_b1  = (const float*)d_in[27];
    const float* dec_w2  = (const float*)d_in[28];
    const float* dec_b2  = (const float*)d_in[29];

    const long long AC   = (long long)SEQ * DMODEL;
    const long long DD   = (long long)DMODEL * DMODEL;
    const long long WH   = (long long)HIDDEN * DMODEL;
    const long long QKVC = (long long)SEQ * 3 * DMODEL;
    const long long SH   = (long long)SEQ * HIDDEN;

    float* mbuf = (float*)d_ws;
    float* xbuf = mbuf + AC;
    float* fbuf = xbuf + AC;
    u16* u = (u16*)(fbuf + AC);
    u16* mb16 = u;  u += AC;
    u16* xb16 = u;  u += AC;
    u16* qkvb = u;  u += QKVC;      // [1024][2304]: q | k | v(cols)
    u16* vt   = u;  u += AC;        // V^T [768][1024]
    u16* ob   = u;  u += AC;        // attention out
    u16* hb   = u;  u += SH;        // ffn hidden

    // converted bf16 weights
    u16* W = u;
    long long woff = 0;
    const long long W_ENC_QKV = woff; woff += 18 * DD;
    const long long W_ENC_WO  = woff; woff += 6 * DD;
    const long long W_ENC_W1  = woff; woff += 6 * WH;
    const long long W_ENC_W2  = woff; woff += 6 * WH;
    const long long W_DEC_QKV = woff; woff += 18 * DD;
    const long long W_DEC_CQKV= woff; woff += 18 * DD;
    const long long W_DEC_WO  = woff; woff += 6 * DD;
    const long long W_DEC_CWO = woff; woff += 6 * DD;
    const long long W_DEC_W1  = woff; woff += 6 * WH;
    const long long W_DEC_W2  = woff; woff += 6 * WH;
    const long long need = (long long)((char*)(W + woff) - (char*)d_ws);
    const bool conv = ((long long)ws_size >= need);

    if (conv) {
        auto cvt = [&](const float* src, long long dst_off, long long per, long long sls, long long dls, int L) {
            dim3 grid((unsigned)((per / 4 + 255) / 256), L);
            hipLaunchKernelGGL(cvt_bf16, grid, dim3(256), 0, stream, src, W + dst_off, per, sls, dls);
        };
        cvt(enc_wq, W_ENC_QKV + 0 * DD, DD, DD, 3 * DD, NLAYER);
        cvt(enc_wk, W_ENC_QKV + 1 * DD, DD, DD, 3 * DD, NLAYER);
        cvt(enc_wv, W_ENC_QKV + 2 * DD, DD, DD, 3 * DD, NLAYER);
        cvt(enc_wo, W_ENC_WO, 6 * DD, 0, 0, 1);
        cvt(enc_w1, W_ENC_W1, 6 * WH, 0, 0, 1);
        cvt(enc_w2, W_ENC_W2, 6 * WH, 0, 0, 1);
        cvt(dec_wq, W_DEC_QKV + 0 * DD, DD, DD, 3 * DD, NLAYER);
        cvt(dec_wk, W_DEC_QKV + 1 * DD, DD, DD, 3 * DD, NLAYER);
        cvt(dec_wv, W_DEC_QKV + 2 * DD, DD, DD, 3 * DD, NLAYER);
        cvt(dec_cwq, W_DEC_CQKV + 0 * DD, DD, DD, 3 * DD, NLAYER);
        cvt(dec_cwk, W_DEC_CQKV + 1 * DD, DD, DD, 3 * DD, NLAYER);
        cvt(dec_cwv, W_DEC_CQKV + 2 * DD, DD, DD, 3 * DD, NLAYER);
        cvt(dec_wo, W_DEC_WO, 6 * DD, 0, 0, 1);
        cvt(dec_cwo, W_DEC_CWO, 6 * DD, 0, 0, 1);
        cvt(dec_w1, W_DEC_W1, 6 * WH, 0, 0, 1);
        cvt(dec_w2, W_DEC_W2, 6 * WH, 0, 0, 1);
    }

    hipLaunchKernelGGL(add_pe, dim3((int)(AC / 256)), dim3(256), 0, stream, xl, pe, mbuf, mb16, (int)AC);

    auto attn = [&](int causal) {
        dim3 grid(SEQ / 64, NHEAD);
        if (causal)
            hipLaunchKernelGGL((attn_fused<1>), grid, dim3(256), 0, stream, qkvb, qkvb + DMODEL, vt, ob);
        else
            hipLaunchKernelGGL((attn_fused<0>), grid, dim3(256), 0, stream, qkvb, qkvb + DMODEL, vt, ob);
    };

    // ---------------- encoder ----------------
    for (int l = 0; l < NLAYER; ++l) {
        if (conv) {
            GArg qkv = { mb16, DMODEL, W + W_ENC_QKV + l * 3 * DD, DMODEL, 0, nullptr,
                         qkvb, 3 * DMODEL, 1, vt, 2 * DMODEL, SEQ, 3 * DMODEL, DMODEL, 0 };
            g64(stream, qkv);
        } else {
            const float* wps[3] = { enc_wq + l * DD, enc_wk + l * DD, enc_wv + l * DD };
            for (int j = 0; j < 3; ++j) {
                GArg a = { mb16, DMODEL, wps[j], DMODEL, 1, nullptr,
                           qkvb + j * DMODEL, 3 * DMODEL, 1,
                           (j == 2) ? vt : nullptr, 0, SEQ, DMODEL, DMODEL, 0 };
                g64(stream, a);
            }
        }
        attn(0);
        GArg wo = { ob, DMODEL,
                    conv ? (const void*)(W + W_ENC_WO + l * DD) : (const void*)(enc_wo + l * DD),
                    DMODEL, conv ? 0 : 1, enc_bo + (long long)l * DMODEL,
                    fbuf, DMODEL, 0, nullptr, 0, SEQ, DMODEL, DMODEL, 0 };
        g64(stream, wo);
        hipLaunchKernelGGL(ln_res_kernel, dim3(SEQ), dim3(256), 0, stream,
                           mbuf, fbuf, enc_lna + (long long)(l * 2 + 0) * DMODEL,
                           enc_lnb + (long long)(l * 2 + 0) * DMODEL, mb16);
        GArg f1 = { mb16, DMODEL,
                    conv ? (const void*)(W + W_ENC_W1 + l * WH) : (const void*)(enc_w1 + l * WH),
                    DMODEL, conv ? 0 : 1, enc_b1 + (long long)l * HIDDEN,
                    hb, HIDDEN, 1, nullptr, 0, SEQ, HIDDEN, DMODEL, 1 };
        g128(stream, f1);
        GArg f2 = { hb, HIDDEN,
                    conv ? (const void*)(W + W_ENC_W2 + l * WH) : (const void*)(enc_w2 + l * WH),
                    HIDDEN, conv ? 0 : 1, enc_b2 + (long long)l * DMODEL,
                    fbuf, DMODEL, 0, nullptr, 0, SEQ, DMODEL, HIDDEN, 0 };
        g64(stream, f2);
        hipLaunchKernelGGL(ln_res_kernel, dim3(SEQ), dim3(256), 0, stream,
                           mbuf, fbuf, enc_lna + (long long)(l * 2 + 1) * DMODEL,
                           enc_lnb + (long long)(l * 2 + 1) * DMODEL, mb16);
    }

    hipLaunchKernelGGL(add_pe, dim3((int)(AC / 256)), dim3(256), 0, stream, dl, pe, xbuf, xb16, (int)AC);

    // ---------------- decoder ----------------
    for (int l = 0; l < NLAYER; ++l) {
        // self attention (causal)
        if (conv) {
            GArg qkv = { xb16, DMODEL, W + W_DEC_QKV + l * 3 * DD, DMODEL, 0, nullptr,
                         qkvb, 3 * DMODEL, 1, vt, 2 * DMODEL, SEQ, 3 * DMODEL, DMODEL, 0 };
            g64(stream, qkv);
        } else {
            const float* wps[3] = { dec_wq + l * DD, dec_wk + l * DD, dec_wv + l * DD };
            for (int j = 0; j < 3; ++j) {
                GArg a = { xb16, DMODEL, wps[j], DMODEL, 1, nullptr,
                           qkvb + j * DMODEL, 3 * DMODEL, 1,
                           (j == 2) ? vt : nullptr, 0, SEQ, DMODEL, DMODEL, 0 };
                g64(stream, a);
            }
        }
        attn(1);
        GArg wo = { ob, DMODEL,
                    conv ? (const void*)(W + W_DEC_WO + l * DD) : (const void*)(dec_wo + l * DD),
                    DMODEL, conv ? 0 : 1, dec_bo + (long long)l * DMODEL,
                    fbuf, DMODEL, 0, nullptr, 0, SEQ, DMODEL, DMODEL, 0 };
        g64(stream, wo);
        hipLaunchKernelGGL(ln_res_kernel, dim3(SEQ), dim3(256), 0, stream,
                           xbuf, fbuf, dec_lna + (long long)(l * 3 + 0) * DMODEL,
                           dec_lnb + (long long)(l * 3 + 0) * DMODEL, xb16);

        // cross attention
        if (conv) {
            GArg q = { xb16, DMODEL, W + W_DEC_CQKV + l * 3 * DD, DMODEL, 0, nullptr,
                       qkvb, 3 * DMODEL, 1, nullptr, 0, SEQ, DMODEL, DMODEL, 0 };
            g64(stream, q);
            GArg kv = { mb16, DMODEL, W + W_DEC_CQKV + l * 3 * DD + DD, DMODEL, 0, nullptr,
                        qkvb + DMODEL, 3 * DMODEL, 1, vt, DMODEL, SEQ, 2 * DMODEL, DMODEL, 0 };
            g64(stream, kv);
        } else {
            GArg q = { xb16, DMODEL, dec_cwq + l * DD, DMODEL, 1, nullptr,
                       qkvb, 3 * DMODEL, 1, nullptr, 0, SEQ, DMODEL, DMODEL, 0 };
            g64(stream, q);
            GArg ck = { mb16, DMODEL, dec_cwk + l * DD, DMODEL, 1, nullptr,
                        qkvb + DMODEL, 3 * DMODEL, 1, nullptr, 0, SEQ, DMODEL, DMODEL, 0 };
            g64(stream, ck);
            GArg cv = { mb16, DMODEL, dec_cwv + l * DD, DMODEL, 1, nullptr,
                        qkvb + 2 * DMODEL, 3 * DMODEL, 1, vt, 0, SEQ, DMODEL, DMODEL, 0 };
            g64(stream, cv);
        }
        attn(0);
        GArg cwo = { ob, DMODEL,
                     conv ? (const void*)(W + W_DEC_CWO + l * DD) : (const void*)(dec_cwo + l * DD),
                     DMODEL, conv ? 0 : 1, dec_cbo + (long long)l * DMODEL,
                     fbuf, DMODEL, 0, nullptr, 0, SEQ, DMODEL, DMODEL, 0 };
        g64(stream, cwo);
        hipLaunchKernelGGL(ln_res_kernel, dim3(SEQ), dim3(256), 0, stream,
                           xbuf, fbuf, dec_lna + (long long)(l * 3 + 1) * DMODEL,
                           dec_lnb + (long long)(l * 3 + 1) * DMODEL, xb16);

        // FFN
        GArg f1 = { xb16, DMODEL,
                    conv ? (const void*)(W + W_DEC_W1 + l * WH) : (const void*)(dec_w1 + l * WH),
                    DMODEL, conv ? 0 : 1, dec_b1 + (long long)l * HIDDEN,
                    hb, HIDDEN, 1, nullptr, 0, SEQ, HIDDEN, DMODEL, 1 };
        g128(stream, f1);
        GArg f2 = { hb, HIDDEN,
                    conv ? (const void*)(W + W_DEC_W2 + l * WH) : (const void*)(dec_w2 + l * WH),
                    HIDDEN, conv ? 0 : 1, dec_b2 + (long long)l * DMODEL,
                    fbuf, DMODEL, 0, nullptr, 0, SEQ, DMODEL, HIDDEN, 0 };
        g64(stream, f2);
        hipLaunchKernelGGL(ln_res_kernel, dim3(SEQ), dim3(256), 0, stream,
                           xbuf, fbuf, dec_lna + (long long)(l * 3 + 2) * DMODEL,
                           dec_lnb + (long long)(l * 3 + 2) * DMODEL, xb16);
    }

    hipLaunchKernelGGL(softmax_f32, dim3(SEQ), dim3(256), 0, stream, xbuf, (float*)d_out, DMODEL);
}

// Round 6
// 1745.870 us; speedup vs baseline: 1.2494x; 1.2494x over previous
//
#include <hip/hip_runtime.h>
#include <math.h>

#define DMODEL 768
#define NHEAD 12
#define DHEAD 64
#define HIDDEN 3072
#define NLAYER 6
#define SEQ 1024
#define AC_ELEMS (SEQ * DMODEL)

typedef unsigned short u16;
typedef __attribute__((ext_vector_type(8))) short short8;
typedef __attribute__((ext_vector_type(4))) float f32x4;

__device__ __forceinline__ u16 f2bf(float f) {
    union { float f; unsigned u; } v; v.f = f;
    unsigned u = v.u;
    return (u16)((u + 0x7fffu + ((u >> 16) & 1u)) >> 16);
}
__device__ __forceinline__ float bf2f(u16 b) {
    union { unsigned u; float f; } v; v.u = ((unsigned)b) << 16; return v.f;
}

// async global->LDS, 16B/lane; LDS base wave-uniform (HW adds lane*16)
__device__ __forceinline__ void async16(const void* g, void* l) {
    __builtin_amdgcn_global_load_lds(
        (const __attribute__((address_space(1))) unsigned int*)g,
        (__attribute__((address_space(3))) unsigned int*)l, 16, 0, 0);
}

// ---------------------------------------------------------------- reductions
__device__ __forceinline__ float block_sum(float v, float* red) {
    int tid = threadIdx.x;
    red[tid] = v;
    __syncthreads();
#pragma unroll
    for (int s = 128; s > 0; s >>= 1) {
        if (tid < s) red[tid] += red[tid + s];
        __syncthreads();
    }
    float r = red[0];
    __syncthreads();
    return r;
}
__device__ __forceinline__ float block_max(float v, float* red) {
    int tid = threadIdx.x;
    red[tid] = v;
    __syncthreads();
#pragma unroll
    for (int s = 128; s > 0; s >>= 1) {
        if (tid < s) red[tid] = fmaxf(red[tid], red[tid + s]);
        __syncthreads();
    }
    float r = red[0];
    __syncthreads();
    return r;
}

// ---------------------------------------------------------------- small kernels
__global__ __launch_bounds__(256) void add_pe(const float* __restrict__ a,
                                              const float* __restrict__ b,
                                              float* __restrict__ o,
                                              u16* __restrict__ ob, int n) {
    int i = blockIdx.x * 256 + threadIdx.x;
    if (i < n) { float v = a[i] + b[i]; o[i] = v; ob[i] = f2bf(v); }
}

__global__ __launch_bounds__(256) void cvt_bf16(const float* __restrict__ src,
                                                u16* __restrict__ dst,
                                                long long per, long long sls, long long dls) {
    long long i = ((long long)blockIdx.x * 256 + threadIdx.x) * 4;
    if (i >= per) return;
    const float* s = src + (long long)blockIdx.y * sls + i;
    u16* d = dst + (long long)blockIdx.y * dls + i;
    float4 v = *(const float4*)s;
    ushort4 o;
    o.x = f2bf(v.x); o.y = f2bf(v.y); o.z = f2bf(v.z); o.w = f2bf(v.w);
    *(ushort4*)d = o;
}

// ---------------------------------------------------------------- MFMA GEMM (2-phase dbuf, param tile/waves, opt split-K)
// C[N x M] = A[N x K](bf16) * B[M x K]^T (+bias) (+relu)
// blockIdx.z = K-split index; z>0 writes f32 partial to C2 (no bias).
// Optional: cols >= vt_col0 stored transposed to vt_out[(col-vt_col0)][row].
template<int TM, int TN, int WR, int WC>
__global__ __launch_bounds__(WR * WC * 64) void gemm_mfma(
    const u16* __restrict__ A, int lda,
    const void* __restrict__ Bp, int ldb, int b_f32,
    const float* __restrict__ bias,
    void* __restrict__ Cp, int ldc, int c_bf16,
    float* __restrict__ C2,
    u16* __restrict__ vt_out, int vt_col0,
    int Ksub, int relu)
{
    constexpr int T  = WR * WC * 64;
    constexpr int FM = TM / (WR * 16), FN = TN / (WC * 16);
    constexpr int NA = TM * 8 / T, NB = TN * 8 / T;
    __shared__ __align__(16) u16 As[2][TM * 64];
    __shared__ __align__(16) u16 Bs[2][TN * 64];

    const int zs = blockIdx.z;
    const u16*   B16 = (const u16*)Bp   + (long long)zs * Ksub;
    const float* B32 = (const float*)Bp + (long long)zs * Ksub;
    A += (long long)zs * Ksub;
    u16*   C16 = (u16*)Cp;
    float* C32 = (float*)Cp;

    const int t = threadIdx.x, lane = t & 63, w = t >> 6;
    const int wy = w / WC, wx = w % WC;
    const int n0 = blockIdx.y * TM, m0 = blockIdx.x * TN;

    auto stage = [&](int b, int k0) {
#pragma unroll
        for (int i = 0; i < NA; ++i) {
            int L = i * T + t;
            int row = L >> 3, cp = L & 7, c = cp ^ (row & 7);
            async16(A + (long long)(n0 + row) * lda + k0 + (c << 3),
                    &As[b][(i * T + w * 64) * 8]);
        }
        if (!b_f32) {
#pragma unroll
            for (int i = 0; i < NB; ++i) {
                int L = i * T + t;
                int row = L >> 3, cp = L & 7, c = cp ^ (row & 7);
                async16(B16 + (long long)(m0 + row) * ldb + k0 + (c << 3),
                        &Bs[b][(i * T + w * 64) * 8]);
            }
        } else {
#pragma unroll
            for (int i = 0; i < NB; ++i) {
                int L = i * T + t;
                int row = L >> 3, cp = L & 7, c = cp ^ (row & 7);
                const float* s = B32 + (long long)(m0 + row) * ldb + k0 + (c << 3);
                float4 x = *(const float4*)s;
                float4 y = *(const float4*)(s + 4);
                uint4 pk;
                pk.x = (unsigned)f2bf(x.x) | ((unsigned)f2bf(x.y) << 16);
                pk.y = (unsigned)f2bf(x.z) | ((unsigned)f2bf(x.w) << 16);
                pk.z = (unsigned)f2bf(y.x) | ((unsigned)f2bf(y.y) << 16);
                pk.w = (unsigned)f2bf(y.z) | ((unsigned)f2bf(y.w) << 16);
                *(uint4*)&Bs[b][row * 64 + cp * 8] = pk;
            }
        }
    };

    const int nk = Ksub / 64;
    stage(0, 0);
    __syncthreads();

    f32x4 acc[FM][FN] = {};

    for (int tt = 0; tt < nk; ++tt) {
        const int cur = tt & 1;
        if (tt + 1 < nk) stage(cur ^ 1, (tt + 1) * 64);   // overlap next tile

        const u16* Ac = As[cur];
        const u16* Bc = Bs[cur];
#pragma unroll
        for (int kk = 0; kk < 2; ++kk) {
            short8 af[FM], bfv[FN];
            const int cb = kk * 4 + (lane >> 4);
#pragma unroll
            for (int m = 0; m < FM; ++m) {
                int R = wy * (TM / WR) + m * 16 + (lane & 15);
                af[m] = *(const short8*)&Ac[R * 64 + ((cb ^ (R & 7)) << 3)];
            }
#pragma unroll
            for (int n = 0; n < FN; ++n) {
                int R = wx * (TN / WC) + n * 16 + (lane & 15);
                bfv[n] = *(const short8*)&Bc[R * 64 + ((cb ^ (R & 7)) << 3)];
            }
#pragma unroll
            for (int m = 0; m < FM; ++m)
#pragma unroll
                for (int n = 0; n < FN; ++n)
                    acc[m][n] = __builtin_amdgcn_mfma_f32_16x16x32_bf16(af[m], bfv[n], acc[m][n], 0, 0, 0);
        }
        __syncthreads();
    }

    const int cj = lane & 15, ci0 = (lane >> 4) << 2;
    const bool z0 = (zs == 0);
#pragma unroll
    for (int m = 0; m < FM; ++m) {
#pragma unroll
        for (int n = 0; n < FN; ++n) {
            int col = m0 + wx * (TN / WC) + n * 16 + cj;
            bool to_vt = z0 && vt_out && (col >= vt_col0);
            float bv = (z0 && bias) ? bias[col] : 0.0f;
#pragma unroll
            for (int r = 0; r < 4; ++r) {
                int row = n0 + wy * (TM / WR) + m * 16 + ci0 + r;
                float v = acc[m][n][r] + bv;
                if (relu) v = fmaxf(v, 0.0f);
                if (!z0)          C2[(long long)row * ldc + col] = v;
                else if (to_vt)   vt_out[(long long)(col - vt_col0) * SEQ + row] = f2bf(v);
                else if (c_bf16)  C16[(long long)row * ldc + col] = f2bf(v);
                else              C32[(long long)row * ldc + col] = v;
            }
        }
    }
}

// ---------------------------------------------------------------- fused flash attention, key-split over blockIdx.z
// Emits UNNORMALIZED O~ (f32) + per-row (m,l) partials; combine kernel merges.
template<int CAUSAL>
__global__ __launch_bounds__(256) void attn_split(
    const u16* __restrict__ Qg,   // qkv base (Q cols)
    const u16* __restrict__ Kg,   // qkv base + DMODEL (K cols)
    const u16* __restrict__ VT,   // [DMODEL][SEQ]
    float* __restrict__ Op,       // [2][SEQ][DMODEL] unnormalized partials
    float* __restrict__ Ml)       // [2][NHEAD][SEQ][2] (m, l)
{
    const int h  = blockIdx.y;
    const int qt = blockIdx.x;
    const int s  = blockIdx.z;    // key-split parity
    const int q0 = qt * 64;
    const int t = threadIdx.x, lane = t & 63, w = t >> 6;

    const int last = CAUSAL ? qt : (SEQ / 64 - 1);

    if (CAUSAL && s > last) {
        // empty split: identity partial
        for (int e = t; e < 64 * 64; e += 256) {
            int r = e >> 6, c = e & 63;
            Op[(long long)s * AC_ELEMS + (long long)(q0 + r) * DMODEL + h * 64 + c] = 0.0f;
        }
        if (t < 64) {
            long long mi = (((long long)s * NHEAD + h) * SEQ + q0 + t) * 2;
            Ml[mi] = -3.0e38f; Ml[mi + 1] = 0.0f;
        }
        return;
    }

    __shared__ __align__(16) u16 Ks[2][64 * 64];
    __shared__ __align__(16) u16 Vs[2][64 * 64];
    __shared__ __align__(16) u16 Ps[4][16 * 64];

    // Q fragments: wave w owns q-rows q0 + w*16 .. +15 (in regs)
    short8 qf[2];
    {
        int qrow = q0 + w * 16 + (lane & 15);
        const u16* qp = Qg + (long long)qrow * (3 * DMODEL) + h * DHEAD + ((lane >> 4) << 3);
        qf[0] = *(const short8*)qp;
        qf[1] = *(const short8*)(qp + 32);
    }

    auto stage = [&](int b, int kt) {
#pragma unroll
        for (int i = 0; i < 2; ++i) {
            int LL = i * 256 + t;
            int row = LL >> 3, cp = LL & 7, c = cp ^ (row & 7);
            async16(Kg + (long long)(kt * 64 + row) * (3 * DMODEL) + h * DHEAD + (c << 3),
                    &Ks[b][(i * 256 + w * 64) * 8]);
            async16(VT + (long long)(h * DHEAD + row) * SEQ + kt * 64 + (c << 3),
                    &Vs[b][(i * 256 + w * 64) * 8]);
        }
    };

    f32x4 o_acc[4] = {};
    float m_r[4], l_r[4];
#pragma unroll
    for (int r = 0; r < 4; ++r) { m_r[r] = -3.0e38f; l_r[r] = 0.f; }

    stage(0, s);
    __syncthreads();

    int buf = 0;
    for (int kt = s; kt <= last; kt += 2) {
        if (kt + 2 <= last) stage(buf ^ 1, kt + 2);   // overlap next tile of this split

        // S = Q K^T
        f32x4 sv[4] = {};
#pragma unroll
        for (int kk = 0; kk < 2; ++kk) {
            const int cb = kk * 4 + (lane >> 4);
#pragma unroll
            for (int n = 0; n < 4; ++n) {
                int R = n * 16 + (lane & 15);
                short8 kf = *(const short8*)&Ks[buf][R * 64 + ((cb ^ (R & 7)) << 3)];
                sv[n] = __builtin_amdgcn_mfma_f32_16x16x32_bf16(qf[kk], kf, sv[n], 0, 0, 0);
            }
        }

        // scale + diagonal causal mask
#pragma unroll
        for (int n = 0; n < 4; ++n) {
            int keyl = n * 16 + (lane & 15);
#pragma unroll
            for (int r = 0; r < 4; ++r) {
                float v = sv[n][r] * 0.125f;
                if (CAUSAL && kt == qt) {
                    int ql = w * 16 + ((lane >> 4) << 2) + r;
                    if (keyl > ql) v -= 10000.0f;
                }
                sv[n][r] = v;
            }
        }

        // online softmax per q-row
#pragma unroll
        for (int r = 0; r < 4; ++r) {
            float vm = fmaxf(fmaxf(sv[0][r], sv[1][r]), fmaxf(sv[2][r], sv[3][r]));
            vm = fmaxf(vm, __shfl_xor(vm, 1));
            vm = fmaxf(vm, __shfl_xor(vm, 2));
            vm = fmaxf(vm, __shfl_xor(vm, 4));
            vm = fmaxf(vm, __shfl_xor(vm, 8));
            float mn = fmaxf(m_r[r], vm);
            float sf = __expf(m_r[r] - mn);
            m_r[r] = mn;
            float rowsum = 0.f;
#pragma unroll
            for (int n = 0; n < 4; ++n) {
                float p = __expf(sv[n][r] - mn);
                sv[n][r] = p;
                rowsum += p;
            }
            rowsum += __shfl_xor(rowsum, 1);
            rowsum += __shfl_xor(rowsum, 2);
            rowsum += __shfl_xor(rowsum, 4);
            rowsum += __shfl_xor(rowsum, 8);
            l_r[r] = l_r[r] * sf + rowsum;
#pragma unroll
            for (int d = 0; d < 4; ++d) o_acc[d][r] *= sf;
        }

        // P (C-layout) -> Ps[w] (wave-private)
#pragma unroll
        for (int n = 0; n < 4; ++n) {
            int jh = lane & 7;
            int chunk = n * 2 + ((lane & 15) >> 3);
#pragma unroll
            for (int r = 0; r < 4; ++r) {
                int q = ((lane >> 4) << 2) + r;
                Ps[w][q * 64 + ((chunk ^ (q & 7)) << 3) + jh] = f2bf(sv[n][r]);
            }
        }

        // O += P V
#pragma unroll
        for (int kk = 0; kk < 2; ++kk) {
            int q = lane & 15;
            int chunk = (lane >> 4) + kk * 4;
            short8 pf = *(const short8*)&Ps[w][q * 64 + ((chunk ^ (q & 7)) << 3)];
            const int cb = kk * 4 + (lane >> 4);
#pragma unroll
            for (int d = 0; d < 4; ++d) {
                int R = d * 16 + (lane & 15);
                short8 vf = *(const short8*)&Vs[buf][R * 64 + ((cb ^ (R & 7)) << 3)];
                o_acc[d] = __builtin_amdgcn_mfma_f32_16x16x32_bf16(pf, vf, o_acc[d], 0, 0, 0);
            }
        }
        __syncthreads();
        buf ^= 1;
    }

    // write unnormalized partials
#pragma unroll
    for (int r = 0; r < 4; ++r) {
        int row = q0 + w * 16 + ((lane >> 4) << 2) + r;
#pragma unroll
        for (int d = 0; d < 4; ++d) {
            int col = h * DHEAD + d * 16 + (lane & 15);
            Op[(long long)s * AC_ELEMS + (long long)row * DMODEL + col] = o_acc[d][r];
        }
        if ((lane & 15) == 0) {
            long long mi = (((long long)s * NHEAD + h) * SEQ + row) * 2;
            Ml[mi] = m_r[r]; Ml[mi + 1] = l_r[r];
        }
    }
}

// ---------------------------------------------------------------- combine split partials -> bf16 O
__global__ __launch_bounds__(192) void attn_combine(const float* __restrict__ Op,
                                                    const float* __restrict__ Ml,
                                                    u16* __restrict__ O) {
    const int row = blockIdx.x;
    const int c0 = threadIdx.x * 4;
    const int h = c0 >> 6;
    long long m0i = (((long long)0 * NHEAD + h) * SEQ + row) * 2;
    long long m1i = (((long long)1 * NHEAD + h) * SEQ + row) * 2;
    float m0 = Ml[m0i], l0 = Ml[m0i + 1];
    float m1 = Ml[m1i], l1 = Ml[m1i + 1];
    float M = fmaxf(m0, m1);
    float w0 = __expf(m0 - M), w1 = __expf(m1 - M);
    float inv = 1.0f / (w0 * l0 + w1 * l1);
    float4 a = *(const float4*)&Op[(long long)row * DMODEL + c0];
    float4 b = *(const float4*)&Op[(long long)AC_ELEMS + (long long)row * DMODEL + c0];
    ushort4 o;
    o.x = f2bf((w0 * a.x + w1 * b.x) * inv);
    o.y = f2bf((w0 * a.y + w1 * b.y) * inv);
    o.z = f2bf((w0 * a.z + w1 * b.z) * inv);
    o.w = f2bf((w0 * a.w + w1 * b.w) * inv);
    *(ushort4*)&O[(long long)row * DMODEL + c0] = o;
}

// ---------------------------------------------------------------- f32 row softmax (final)
__global__ __launch_bounds__(256) void softmax_f32(const float* __restrict__ in,
                                                   float* __restrict__ out, int width) {
    const float* row = in + (long long)blockIdx.x * width;
    float* orow = out + (long long)blockIdx.x * width;
    int tid = threadIdx.x;
    __shared__ float red[256];
    int nf4 = width >> 2;
    float4 v = {-1e30f, -1e30f, -1e30f, -1e30f};
    if (tid < nf4) v = ((const float4*)row)[tid];
    float mx = fmaxf(fmaxf(v.x, v.y), fmaxf(v.z, v.w));
    mx = block_max(mx, red);
    float4 e = {0.f, 0.f, 0.f, 0.f};
    float s = 0.f;
    if (tid < nf4) {
        e.x = __expf(v.x - mx); e.y = __expf(v.y - mx);
        e.z = __expf(v.z - mx); e.w = __expf(v.w - mx);
        s = e.x + e.y + e.z + e.w;
    }
    s = block_sum(s, red);
    float inv = 1.0f / s;
    if (tid < nf4) {
        e.x *= inv; e.y *= inv; e.z *= inv; e.w *= inv;
        ((float4*)orow)[tid] = e;
    }
}

// ---------------------------------------------------------------- x = LN(x + fx (+fx2)); emits f32 + bf16
__global__ __launch_bounds__(256) void ln_res_kernel(float* __restrict__ x,
                                                     const float* __restrict__ fx,
                                                     const float* __restrict__ fx2,
                                                     const float* __restrict__ ga,
                                                     const float* __restrict__ gb,
                                                     u16* __restrict__ xb) {
    long long row = blockIdx.x;
    float* xr = x + row * DMODEL;
    const float* fr = fx + row * DMODEL;
    u16* xbr = xb + row * DMODEL;
    int tid = threadIdx.x;
    __shared__ float red[256];

    float4 tv = {0.f, 0.f, 0.f, 0.f};
    if (tid < 192) {
        float4 a = ((const float4*)xr)[tid];
        float4 f = ((const float4*)fr)[tid];
        tv.x = a.x + f.x; tv.y = a.y + f.y; tv.z = a.z + f.z; tv.w = a.w + f.w;
        if (fx2) {
            float4 g = ((const float4*)(fx2 + row * DMODEL))[tid];
            tv.x += g.x; tv.y += g.y; tv.z += g.z; tv.w += g.w;
        }
    }
    float sum = tv.x + tv.y + tv.z + tv.w;
    sum = block_sum(sum, red);
    float mean = sum * (1.0f / (float)DMODEL);

    float4 d = {0.f, 0.f, 0.f, 0.f};
    float ss = 0.f;
    if (tid < 192) {
        d.x = tv.x - mean; d.y = tv.y - mean; d.z = tv.z - mean; d.w = tv.w - mean;
        ss = d.x * d.x + d.y * d.y + d.z * d.z + d.w * d.w;
    }
    ss = block_sum(ss, red);
    float stdv = sqrtf(ss / (float)(DMODEL - 1));
    float inv = 1.0f / (stdv + 1e-6f);

    if (tid < 192) {
        float4 A = ((const float4*)ga)[tid];
        float4 B = ((const float4*)gb)[tid];
        float4 o;
        o.x = A.x * d.x * inv + B.x;
        o.y = A.y * d.y * inv + B.y;
        o.z = A.z * d.z * inv + B.z;
        o.w = A.w * d.w * inv + B.w;
        ((float4*)xr)[tid] = o;
        ushort4 ob;
        ob.x = f2bf(o.x); ob.y = f2bf(o.y); ob.z = f2bf(o.z); ob.w = f2bf(o.w);
        ((ushort4*)xbr)[tid] = ob;
    }
}

// ---------------------------------------------------------------- host
struct GArg {
    const u16* A; int lda;
    const void* B; int ldb; int b_f32;
    const float* bias;
    void* C; int ldc; int c_bf16;
    u16* vt; int vt_col0;
    int N, M, K; int relu;
};
template<int TM, int TN, int WR, int WC>
static inline void glaunch(hipStream_t st, const GArg& a, int splitk = 1, float* C2 = nullptr) {
    dim3 grid(a.M / TN, a.N / TM, splitk);
    hipLaunchKernelGGL((gemm_mfma<TM, TN, WR, WC>), grid, dim3(WR * WC * 64), 0, st,
                       a.A, a.lda, a.B, a.ldb, a.b_f32, a.bias, a.C, a.ldc, a.c_bf16,
                       C2, a.vt, a.vt_col0, a.K / splitk, a.relu);
}

extern "C" void kernel_launch(void* const* d_in, const int* in_sizes, int n_in,
                              void* d_out, int out_size, void* d_ws, size_t ws_size,
                              hipStream_t stream) {
    const float* xl      = (const float*)d_in[0];
    const float* dl      = (const float*)d_in[1];
    const float* pe      = (const float*)d_in[2];
    const float* enc_wq  = (const float*)d_in[3];
    const float* enc_wk  = (const float*)d_in[4];
    const float* enc_wv  = (const float*)d_in[5];
    const float* enc_wo  = (const float*)d_in[6];
    const float* enc_bo  = (const float*)d_in[7];
    const float* enc_lna = (const float*)d_in[8];
    const float* enc_lnb = (const float*)d_in[9];
    const float* enc_w1  = (const float*)d_in[10];
    const float* enc_b1  = (const float*)d_in[11];
    const float* enc_w2  = (const float*)d_in[12];
    const float* enc_b2  = (const float*)d_in[13];
    const float* dec_wq  = (const float*)d_in[14];
    const float* dec_wk  = (const float*)d_in[15];
    const float* dec_wv  = (const float*)d_in[16];
    const float* dec_wo  = (const float*)d_in[17];
    const float* dec_bo  = (const float*)d_in[18];
    const float* dec_cwq = (const float*)d_in[19];
    const float* dec_cwk = (const float*)d_in[20];
    const float* dec_cwv = (const float*)d_in[21];
    const float* dec_cwo = (const float*)d_in[22];
    const float* dec_cbo = (const float*)d_in[23];
    const float* dec_lna = (const float*)d_in[24];
    const float* dec_lnb = (const float*)d_in[25];
    const float* dec_w1  = (const float*)d_in[26];
    const float* dec_b1  = (const float*)d_in[27];
    const float* dec_w2  = (const float*)d_in[28];
    const float* dec_b2  = (const float*)d_in[29];

    const long long AC   = AC_ELEMS;
    const long long DD   = (long long)DMODEL * DMODEL;
    const long long WH   = (long long)HIDDEN * DMODEL;
    const long long QKVC = (long long)SEQ * 3 * DMODEL;
    const long long SH   = (long long)SEQ * HIDDEN;

    float* mbuf  = (float*)d_ws;
    float* xbuf  = mbuf + AC;
    float* fbuf  = xbuf + AC;
    float* fbuf2 = fbuf + AC;
    float* Opart = fbuf2 + AC;                 // [2][SEQ][DMODEL]
    float* Ml    = Opart + 2 * AC;             // [2][NHEAD][SEQ][2]
    u16* u = (u16*)(Ml + 2LL * NHEAD * SEQ * 2);
    u16* mb16 = u;  u += AC;
    u16* xb16 = u;  u += AC;
    u16* qkvb = u;  u += QKVC;      // [1024][2304]: q | k | v
    u16* vt   = u;  u += AC;        // V^T [768][1024]
    u16* ob   = u;  u += AC;        // attention out
    u16* hb   = u;  u += SH;        // ffn hidden

    // converted bf16 weights
    u16* W = u;
    long long woff = 0;
    const long long W_ENC_QKV = woff; woff += 18 * DD;
    const long long W_ENC_WO  = woff; woff += 6 * DD;
    const long long W_ENC_W1  = woff; woff += 6 * WH;
    const long long W_ENC_W2  = woff; woff += 6 * WH;
    const long long W_DEC_QKV = woff; woff += 18 * DD;
    const long long W_DEC_CQKV= woff; woff += 18 * DD;
    const long long W_DEC_WO  = woff; woff += 6 * DD;
    const long long W_DEC_CWO = woff; woff += 6 * DD;
    const long long W_DEC_W1  = woff; woff += 6 * WH;
    const long long W_DEC_W2  = woff; woff += 6 * WH;
    const long long need = (long long)((char*)(W + woff) - (char*)d_ws);
    const bool conv = ((long long)ws_size >= need);

    if (conv) {
        auto cvt = [&](const float* src, long long dst_off, long long per, long long sls, long long dls, int L) {
            dim3 grid((unsigned)((per / 4 + 255) / 256), L);
            hipLaunchKernelGGL(cvt_bf16, grid, dim3(256), 0, stream, src, W + dst_off, per, sls, dls);
        };
        cvt(enc_wq, W_ENC_QKV + 0 * DD, DD, DD, 3 * DD, NLAYER);
        cvt(enc_wk, W_ENC_QKV + 1 * DD, DD, DD, 3 * DD, NLAYER);
        cvt(enc_wv, W_ENC_QKV + 2 * DD, DD, DD, 3 * DD, NLAYER);
        cvt(enc_wo, W_ENC_WO, 6 * DD, 0, 0, 1);
        cvt(enc_w1, W_ENC_W1, 6 * WH, 0, 0, 1);
        cvt(enc_w2, W_ENC_W2, 6 * WH, 0, 0, 1);
        cvt(dec_wq, W_DEC_QKV + 0 * DD, DD, DD, 3 * DD, NLAYER);
        cvt(dec_wk, W_DEC_QKV + 1 * DD, DD, DD, 3 * DD, NLAYER);
        cvt(dec_wv, W_DEC_QKV + 2 * DD, DD, DD, 3 * DD, NLAYER);
        cvt(dec_cwq, W_DEC_CQKV + 0 * DD, DD, DD, 3 * DD, NLAYER);
        cvt(dec_cwk, W_DEC_CQKV + 1 * DD, DD, DD, 3 * DD, NLAYER);
        cvt(dec_cwv, W_DEC_CQKV + 2 * DD, DD, DD, 3 * DD, NLAYER);
        cvt(dec_wo, W_DEC_WO, 6 * DD, 0, 0, 1);
        cvt(dec_cwo, W_DEC_CWO, 6 * DD, 0, 0, 1);
        cvt(dec_w1, W_DEC_W1, 6 * WH, 0, 0, 1);
        cvt(dec_w2, W_DEC_W2, 6 * WH, 0, 0, 1);
    }

    hipLaunchKernelGGL(add_pe, dim3((int)(AC / 256)), dim3(256), 0, stream, xl, pe, mbuf, mb16, (int)AC);

    auto attn = [&](int causal) {
        dim3 grid(SEQ / 64, NHEAD, 2);
        if (causal)
            hipLaunchKernelGGL((attn_split<1>), grid, dim3(256), 0, stream,
                               qkvb, qkvb + DMODEL, vt, Opart, Ml);
        else
            hipLaunchKernelGGL((attn_split<0>), grid, dim3(256), 0, stream,
                               qkvb, qkvb + DMODEL, vt, Opart, Ml);
        hipLaunchKernelGGL(attn_combine, dim3(SEQ), dim3(192), 0, stream, Opart, Ml, ob);
    };

    // ---------------- encoder ----------------
    for (int l = 0; l < NLAYER; ++l) {
        if (conv) {
            GArg qkv = { mb16, DMODEL, W + W_ENC_QKV + l * 3 * DD, DMODEL, 0, nullptr,
                         qkvb, 3 * DMODEL, 1, vt, 2 * DMODEL, SEQ, 3 * DMODEL, DMODEL, 0 };
            glaunch<64, 64, 2, 2>(stream, qkv);
        } else {
            const float* wps[3] = { enc_wq + l * DD, enc_wk + l * DD, enc_wv + l * DD };
            for (int j = 0; j < 3; ++j) {
                GArg a = { mb16, DMODEL, wps[j], DMODEL, 1, nullptr,
                           qkvb + j * DMODEL, 3 * DMODEL, 1,
                           (j == 2) ? vt : nullptr, 0, SEQ, DMODEL, DMODEL, 0 };
                glaunch<32, 32, 1, 1>(stream, a);
            }
        }
        attn(0);
        GArg wo = { ob, DMODEL,
                    conv ? (const void*)(W + W_ENC_WO + l * DD) : (const void*)(enc_wo + l * DD),
                    DMODEL, conv ? 0 : 1, enc_bo + (long long)l * DMODEL,
                    fbuf, DMODEL, 0, nullptr, 0, SEQ, DMODEL, DMODEL, 0 };
        glaunch<32, 32, 1, 1>(stream, wo);
        hipLaunchKernelGGL(ln_res_kernel, dim3(SEQ), dim3(256), 0, stream,
                           mbuf, fbuf, (const float*)nullptr,
                           enc_lna + (long long)(l * 2 + 0) * DMODEL,
                           enc_lnb + (long long)(l * 2 + 0) * DMODEL, mb16);
        GArg f1 = { mb16, DMODEL,
                    conv ? (const void*)(W + W_ENC_W1 + l * WH) : (const void*)(enc_w1 + l * WH),
                    DMODEL, conv ? 0 : 1, enc_b1 + (long long)l * HIDDEN,
                    hb, HIDDEN, 1, nullptr, 0, SEQ, HIDDEN, DMODEL, 1 };
        glaunch<64, 64, 2, 2>(stream, f1);
        GArg f2 = { hb, HIDDEN,
                    conv ? (const void*)(W + W_ENC_W2 + l * WH) : (const void*)(enc_w2 + l * WH),
                    HIDDEN, conv ? 0 : 1, enc_b2 + (long long)l * DMODEL,
                    fbuf, DMODEL, 0, nullptr, 0, SEQ, DMODEL, HIDDEN, 0 };
        glaunch<64, 64, 2, 2>(stream, f2, 2, fbuf2);
        hipLaunchKernelGGL(ln_res_kernel, dim3(SEQ), dim3(256), 0, stream,
                           mbuf, fbuf, fbuf2,
                           enc_lna + (long long)(l * 2 + 1) * DMODEL,
                           enc_lnb + (long long)(l * 2 + 1) * DMODEL, mb16);
    }

    hipLaunchKernelGGL(add_pe, dim3((int)(AC / 256)), dim3(256), 0, stream, dl, pe, xbuf, xb16, (int)AC);

    // ---------------- decoder ----------------
    for (int l = 0; l < NLAYER; ++l) {
        // self attention (causal)
        if (conv) {
            GArg qkv = { xb16, DMODEL, W + W_DEC_QKV + l * 3 * DD, DMODEL, 0, nullptr,
                         qkvb, 3 * DMODEL, 1, vt, 2 * DMODEL, SEQ, 3 * DMODEL, DMODEL, 0 };
            glaunch<64, 64, 2, 2>(stream, qkv);
        } else {
            const float* wps[3] = { dec_wq + l * DD, dec_wk + l * DD, dec_wv + l * DD };
            for (int j = 0; j < 3; ++j) {
                GArg a = { xb16, DMODEL, wps[j], DMODEL, 1, nullptr,
                           qkvb + j * DMODEL, 3 * DMODEL, 1,
                           (j == 2) ? vt : nullptr, 0, SEQ, DMODEL, DMODEL, 0 };
                glaunch<32, 32, 1, 1>(stream, a);
            }
        }
        attn(1);
        GArg wo = { ob, DMODEL,
                    conv ? (const void*)(W + W_DEC_WO + l * DD) : (const void*)(dec_wo + l * DD),
                    DMODEL, conv ? 0 : 1, dec_bo + (long long)l * DMODEL,
                    fbuf, DMODEL, 0, nullptr, 0, SEQ, DMODEL, DMODEL, 0 };
        glaunch<32, 32, 1, 1>(stream, wo);
        hipLaunchKernelGGL(ln_res_kernel, dim3(SEQ), dim3(256), 0, stream,
                           xbuf, fbuf, (const float*)nullptr,
                           dec_lna + (long long)(l * 3 + 0) * DMODEL,
                           dec_lnb + (long long)(l * 3 + 0) * DMODEL, xb16);

        // cross attention
        if (conv) {
            GArg q = { xb16, DMODEL, W + W_DEC_CQKV + l * 3 * DD, DMODEL, 0, nullptr,
                       qkvb, 3 * DMODEL, 1, nullptr, 0, SEQ, DMODEL, DMODEL, 0 };
            glaunch<32, 32, 1, 1>(stream, q);
            GArg kv = { mb16, DMODEL, W + W_DEC_CQKV + l * 3 * DD + DD, DMODEL, 0, nullptr,
                        qkvb + DMODEL, 3 * DMODEL, 1, vt, DMODEL, SEQ, 2 * DMODEL, DMODEL, 0 };
            glaunch<32, 32, 1, 1>(stream, kv);
        } else {
            GArg q = { xb16, DMODEL, dec_cwq + l * DD, DMODEL, 1, nullptr,
                       qkvb, 3 * DMODEL, 1, nullptr, 0, SEQ, DMODEL, DMODEL, 0 };
            glaunch<32, 32, 1, 1>(stream, q);
            GArg ck = { mb16, DMODEL, dec_cwk + l * DD, DMODEL, 1, nullptr,
                        qkvb + DMODEL, 3 * DMODEL, 1, nullptr, 0, SEQ, DMODEL, DMODEL, 0 };
            glaunch<32, 32, 1, 1>(stream, ck);
            GArg cv = { mb16, DMODEL, dec_cwv + l * DD, DMODEL, 1, nullptr,
                        qkvb + 2 * DMODEL, 3 * DMODEL, 1, vt, 0, SEQ, DMODEL, DMODEL, 0 };
            glaunch<32, 32, 1, 1>(stream, cv);
        }
        attn(0);
        GArg cwo = { ob, DMODEL,
                     conv ? (const void*)(W + W_DEC_CWO + l * DD) : (const void*)(dec_cwo + l * DD),
                     DMODEL, conv ? 0 : 1, dec_cbo + (long long)l * DMODEL,
                     fbuf, DMODEL, 0, nullptr, 0, SEQ, DMODEL, DMODEL, 0 };
        glaunch<32, 32, 1, 1>(stream, cwo);
        hipLaunchKernelGGL(ln_res_kernel, dim3(SEQ), dim3(256), 0, stream,
                           xbuf, fbuf, (const float*)nullptr,
                           dec_lna + (long long)(l * 3 + 1) * DMODEL,
                           dec_lnb + (long long)(l * 3 + 1) * DMODEL, xb16);

        // FFN
        GArg f1 = { xb16, DMODEL,
                    conv ? (const void*)(W + W_DEC_W1 + l * WH) : (const void*)(dec_w1 + l * WH),
                    DMODEL, conv ? 0 : 1, dec_b1 + (long long)l * HIDDEN,
                    hb, HIDDEN, 1, nullptr, 0, SEQ, HIDDEN, DMODEL, 1 };
        glaunch<64, 64, 2, 2>(stream, f1);
        GArg f2 = { hb, HIDDEN,
                    conv ? (const void*)(W + W_DEC_W2 + l * WH) : (const void*)(dec_w2 + l * WH),
                    HIDDEN, conv ? 0 : 1, dec_b2 + (long long)l * DMODEL,
                    fbuf, DMODEL, 0, nullptr, 0, SEQ, DMODEL, HIDDEN, 0 };
        glaunch<64, 64, 2, 2>(stream, f2, 2, fbuf2);
        hipLaunchKernelGGL(ln_res_kernel, dim3(SEQ), dim3(256), 0, stream,
                           xbuf, fbuf, fbuf2,
                           dec_lna + (long long)(l * 3 + 2) * DMODEL,
                           dec_lnb + (long long)(l * 3 + 2) * DMODEL, xb16);
    }

    hipLaunchKernelGGL(softmax_f32, dim3(SEQ), dim3(256), 0, stream, xbuf, (float*)d_out, DMODEL);
}